// Round 15
// baseline (563.733 us; speedup 1.0000x reference)
//
#include <hip/hip_runtime.h>
#include <hip/hip_bf16.h>

typedef __bf16 bf16_t;
typedef __bf16 bf16x8 __attribute__((ext_vector_type(8)));
typedef float f32x4 __attribute__((ext_vector_type(4)));

static __device__ __forceinline__ f32x4 mfma16(bf16x8 a, bf16x8 b, f32x4 c) {
  return __builtin_amdgcn_mfma_f32_16x16x32_bf16(a, b, c, 0, 0, 0);
}

static __device__ __forceinline__ void gload16(const void* g, void* l) {
  __builtin_amdgcn_global_load_lds(
      (const __attribute__((address_space(1))) void*)g,
      (__attribute__((address_space(3))) void*)l, 16, 0, 0);
}

#define BAR() __builtin_amdgcn_s_barrier()
#define SCHED0() __builtin_amdgcn_sched_barrier(0)
#define MEMFENCE() asm volatile("" ::: "memory")
#define BARF() do { BAR(); MEMFENCE(); SCHED0(); } while (0)
#define WAITVM4() do { asm volatile("s_waitcnt vmcnt(4)" ::: "memory"); SCHED0(); } while (0)
#define WAITVM0() do { asm volatile("s_waitcnt vmcnt(0)" ::: "memory"); SCHED0(); } while (0)
#define WAITLGKM0() do { asm volatile("s_waitcnt lgkmcnt(0)" ::: "memory"); SCHED0(); } while (0)
#define SP1 __builtin_amdgcn_s_setprio(1)
#define SP0 __builtin_amdgcn_s_setprio(0)

// == merged prep: cvt(x->bf16) | W^T cvt | CPB-MLP + bias expand (per-head) ==
// blocks [0,2048): cvt; [2048,3776): wTq; [3776,4352): wTp; [4352,4376): bias.
// Bias block h: tid<225 recomputes CPB column h (wave-uniform loads, ~2us
// total), then expands via rel_idx to bias[h][64][64]. Replaces the separate
// bias_expand launch (R9 attribution: this fold is innocent; the regression
// there was the attn-side scattered gather).
__global__ __launch_bounds__(256) void prep_kernel(
    const float* __restrict__ x, bf16_t* __restrict__ xb,
    const float* __restrict__ qkv_w, bf16_t* __restrict__ wTq,
    const float* __restrict__ proj_w, bf16_t* __restrict__ wTp,
    const float* __restrict__ table, const float* __restrict__ w1,
    const float* __restrict__ b1, const float* __restrict__ w2,
    const int* __restrict__ rel_idx, float* __restrict__ bias) {
  __shared__ __align__(16) char sm[4352];
  int blk = blockIdx.x;
  int tid = threadIdx.x;
  if (blk < 2048) {  // ---- cvt: x f32 -> xb bf16, n8 = 6291456 ----
    const int n8 = 6291456, stride = 2048 * 256;
    for (int i = blk * 256 + tid; i < n8; i += stride) {
      float4 a = ((const float4*)x)[2 * i];
      float4 b = ((const float4*)x)[2 * i + 1];
      bf16x8 w = {(bf16_t)a.x, (bf16_t)a.y, (bf16_t)a.z, (bf16_t)a.w,
                  (bf16_t)b.x, (bf16_t)b.y, (bf16_t)b.z, (bf16_t)b.w};
      ((bf16x8*)xb)[i] = w;
    }
    return;
  }
  if (blk < 4352) {  // ---- transpose W[K][N] -> WT[N][K] bf16, 32x32 tiles ----
    const float* W;
    bf16_t* WT;
    int K = 768, N, r;
    if (blk < 3776) { W = qkv_w; WT = wTq; N = 2304; r = blk - 2048; }
    else            { W = proj_w; WT = wTp; N = 768;  r = blk - 3776; }
    int nbx = N / 32;
    int n0 = (r % nbx) * 32, k0 = (r / nbx) * 32;
    float (*tile)[33] = (float(*)[33])sm;
    int tx = tid & 31, ty = tid >> 5;
#pragma unroll
    for (int i = 0; i < 32; i += 8)
      tile[ty + i][tx] = W[(size_t)(k0 + ty + i) * N + n0 + tx];
    __syncthreads();
#pragma unroll
    for (int i = 0; i < 32; i += 8)
      WT[(size_t)(n0 + ty + i) * K + k0 + tx] = (bf16_t)tile[tx][ty + i];
    return;
  }
  {  // ---- bias: one block per head; recompute CPB column + expand ----
    float* sbuf = (float*)sm;  // 225 floats
    int h = blk - 4352;
    if (tid < 225) {
      float c0 = table[2 * tid], c1 = table[2 * tid + 1];
      float s = 0.f;
      for (int j = 0; j < 512; ++j) {  // w1/b1/w2 loads wave-uniform -> scalar
        float hh = c0 * w1[j] + c1 * w1[512 + j] + b1[j];
        s += fmaxf(hh, 0.f) * w2[j * 24 + h];
      }
      sbuf[tid] = s;
    }
    __syncthreads();
    for (int nm = tid; nm < 4096; nm += 256)
      bias[h * 4096 + nm] = sbuf[rel_idx[nm]];
  }
}

// ============ GEMM: 256x256, BK=64, 8-phase counted-vmcnt (round-4/6) =======
// Known-good schedule (R6/R8/R10/R13/R14: QKV ~250us, MfmaUtil 41%, 0
// conflicts, stable +-2us over 6 runs). Do not perturb: R5 (4-phase) and
// R7 (counted-lgkm prefetch) both regressed.
template <int EPI, int NCOLS, int K>
__global__ __launch_bounds__(512, 2) void gemm_kernel(
    const bf16_t* __restrict__ A, const bf16_t* __restrict__ BT,
    const float* __restrict__ bias, void* __restrict__ outp) {
  constexpr int NT = NCOLS / 256;
  constexpr int Kb = K * 2;
  constexpr int nk = K / 64;
  constexpr int nIt = nk / 2;
  __shared__ __align__(16) char lds[131072];
  int tid = threadIdx.x;
  int wave = tid >> 6, lane = tid & 63;
  int wm = wave >> 2, wn = wave & 3;
  int cpx = gridDim.x >> 3;
  int wg = (blockIdx.x & 7) * cpx + (blockIdx.x >> 3);
  int mt = wg / NT, nt = wg % NT;
  int m0 = mt * 256, n0 = nt * 256;

  int srow = tid >> 3;
  int sbc = ((tid & 7) << 4) ^ ((srow & 7) << 4);
  const char* Ag = (const char*)A + (size_t)(m0 + srow) * Kb + sbc;
  const char* Bg = (const char*)BT + (size_t)(n0 + srow) * Kb + sbc;
  char* Al = lds + tid * 16;
  char* Bl = lds + 65536 + tid * 16;

#define ST_A(B_, H_, KT_)                                                     \
  do {                                                                        \
    gload16(Ag + (size_t)((H_) * 128) * Kb + (KT_) * 128,                     \
            Al + (B_) * 32768 + (H_) * 16384);                                \
    gload16(Ag + (size_t)((H_) * 128 + 64) * Kb + (KT_) * 128,                \
            Al + (B_) * 32768 + (H_) * 16384 + 8192);                         \
  } while (0)
#define ST_B(B_, H_, KT_)                                                     \
  do {                                                                        \
    gload16(Bg + (size_t)((H_) * 128) * Kb + (KT_) * 128,                     \
            Bl + (B_) * 32768 + (H_) * 16384);                                \
    gload16(Bg + (size_t)((H_) * 128 + 64) * Kb + (KT_) * 128,                \
            Bl + (B_) * 32768 + (H_) * 16384 + 8192);                         \
  } while (0)

  int r15 = lane & 15, hi = lane >> 4;
  int swz = (lane & 7) << 4;
  int c0 = (hi << 4) ^ swz;         // kk=0 byte-col
  int c1 = (64 | (hi << 4)) ^ swz;  // kk=1 byte-col
  const char* aBase = lds + wm * 16384 + r15 * 128;
  const char* bBase = lds + 65536 + (wn >> 1) * 16384 + (wn & 1) * 8192 + r15 * 128;

#define RD_B8(B_)                                                             \
  do {                                                                        \
    _Pragma("unroll") for (int nc = 0; nc < 4; ++nc) {                        \
      bfr[nc][0] = *(const bf16x8*)(bBase + (B_) * 32768 + nc * 2048 + c0);   \
      bfr[nc][1] = *(const bf16x8*)(bBase + (B_) * 32768 + nc * 2048 + c1);   \
    }                                                                         \
  } while (0)
#define RD_A4(B_, MRLO, C_)                                                   \
  do {                                                                        \
    _Pragma("unroll") for (int m_ = 0; m_ < 4; ++m_)                          \
        af[m_] = *(const bf16x8*)(aBase + (B_) * 32768 + ((MRLO) + m_) * 2048 + (C_)); \
  } while (0)
#define MF16(MRLO, KKI)                                                       \
  do {                                                                        \
    _Pragma("unroll") for (int m_ = 0; m_ < 4; ++m_)                          \
        _Pragma("unroll") for (int nc = 0; nc < 4; ++nc)                      \
            acc[(MRLO) + m_][nc] =                                            \
        mfma16(af[m_], bfr[nc][KKI], acc[(MRLO) + m_][nc]);                   \
  } while (0)

  f32x4 acc[8][4] = {};
  ST_B(0, 0, 0); ST_B(0, 1, 0);
  ST_A(0, 0, 0); ST_A(0, 1, 0);
  ST_B(1, 0, 1); ST_B(1, 1, 1);
  WAITVM4();
  BARF();

  for (int it = 0; it < nIt - 1; ++it) {
    int T = 2 * it;
    bf16x8 af[4], bfr[4][2];
    // ph1
    RD_B8(0); RD_A4(0, 0, c0);
    ST_A(1, 0, T + 1); ST_A(1, 1, T + 1);
    BAR(); WAITLGKM0();
    SP1; MF16(0, 0); SP0;
    BARF();
    // ph2
    RD_A4(0, 4, c0);
    ST_B(0, 0, T + 2);
    BAR(); WAITLGKM0();
    SP1; MF16(4, 0); SP0;
    BARF();
    // ph3
    RD_A4(0, 0, c1);
    ST_B(0, 1, T + 2);
    BAR(); WAITLGKM0();
    SP1; MF16(0, 1); SP0;
    BARF();
    // ph4
    RD_A4(0, 4, c1);
    BAR(); WAITLGKM0();
    SP1; MF16(4, 1); SP0;
    WAITVM4();
    BARF();
    // ph5
    RD_B8(1); RD_A4(1, 0, c0);
    ST_A(0, 0, T + 2);
    BAR(); WAITLGKM0();
    SP1; MF16(0, 0); SP0;
    BARF();
    // ph6
    RD_A4(1, 4, c0);
    ST_A(0, 1, T + 2);
    BAR(); WAITLGKM0();
    SP1; MF16(4, 0); SP0;
    BARF();
    // ph7
    RD_A4(1, 0, c1);
    ST_B(1, 0, T + 3);
    BAR(); WAITLGKM0();
    SP1; MF16(0, 1); SP0;
    BARF();
    // ph8
    RD_A4(1, 4, c1);
    ST_B(1, 1, T + 3);
    BAR(); WAITLGKM0();
    SP1; MF16(4, 1); SP0;
    WAITVM4();
    BARF();
  }
  {  // peeled final iter: T = nk-2; only A(nk-1) still needs staging (ph1)
    bf16x8 af[4], bfr[4][2];
    RD_B8(0); RD_A4(0, 0, c0);
    ST_A(1, 0, nk - 1); ST_A(1, 1, nk - 1);
    BAR(); WAITLGKM0();
    SP1; MF16(0, 0); SP0;
    BARF();
    RD_A4(0, 4, c0);
    BAR(); WAITLGKM0();
    SP1; MF16(4, 0); SP0;
    BARF();
    RD_A4(0, 0, c1);
    BAR(); WAITLGKM0();
    SP1; MF16(0, 1); SP0;
    BARF();
    RD_A4(0, 4, c1);
    BAR(); WAITLGKM0();
    SP1; MF16(4, 1); SP0;
    WAITVM0();
    BARF();
    RD_B8(1); RD_A4(1, 0, c0);
    BAR(); WAITLGKM0();
    SP1; MF16(0, 0); SP0;
    BARF();
    RD_A4(1, 4, c0);
    BAR(); WAITLGKM0();
    SP1; MF16(4, 0); SP0;
    BARF();
    RD_A4(1, 0, c1);
    BAR(); WAITLGKM0();
    SP1; MF16(0, 1); SP0;
    BARF();
    RD_A4(1, 4, c1);
    BAR(); WAITLGKM0();
    SP1; MF16(4, 1); SP0;
  }

  // ---- epilogue ----
  int hi4 = hi * 4;
  if constexpr (EPI == 0) {
    bf16_t* out = (bf16_t*)outp;
    int sidx = n0 / 768;
#pragma unroll
    for (int mr = 0; mr < 8; ++mr)
#pragma unroll
      for (int nc = 0; nc < 4; ++nc) {
        int gcol = n0 + wn * 64 + nc * 16 + r15;
        int within = gcol - sidx * 768;
        int h = within >> 5, d = within & 31;
        float bv = bias[gcol];
#pragma unroll
        for (int j = 0; j < 4; ++j) {
          int grow = m0 + wm * 128 + mr * 16 + hi4 + j;
          int bwin = grow >> 6, nn = grow & 63;
          size_t off = ((((size_t)sidx * 1024 + bwin) * 24 + h) * 64 + nn) * 32 + d;
          out[off] = (bf16_t)(acc[mr][nc][j] + bv);
        }
      }
  } else {
    float* out = (float*)outp;
#pragma unroll
    for (int mr = 0; mr < 8; ++mr)
#pragma unroll
      for (int nc = 0; nc < 4; ++nc) {
        int gcol = n0 + wn * 64 + nc * 16 + r15;
        float bv = bias[gcol];
#pragma unroll
        for (int j = 0; j < 4; ++j) {
          int grow = m0 + wm * 128 + mr * 16 + hi4 + j;
          out[(size_t)grow * NCOLS + gcol] = acc[mr][nc][j] + bv;
        }
      }
  }
#undef ST_A
#undef ST_B
#undef RD_B8
#undef RD_A4
#undef MF16
}

// ---------------- Attention: one wave per (window, head) ----------------
// Byte-identical to R14 (best measured). LDS 13824 is alignment-minimal:
// ds_read_b128 rows must be 16B-aligned => strides multiple of 8 elems;
// 40/72 are the smallest conflict-free choices. b-major grid (neutral).
__global__ __launch_bounds__(64) void attn_kernel(
    const bf16_t* __restrict__ qkv, const float* __restrict__ bias,
    const float* __restrict__ logit_scale, bf16_t* __restrict__ attn_out) {
  __shared__ __align__(16) char smem[13824];
  bf16_t (*qs)[40] = (bf16_t(*)[40])smem;            // [0, 5120)
  bf16_t (*kk)[40] = (bf16_t(*)[40])(smem + 5120);   // [5120, 10240)
  bf16_t (*ps)[72] = (bf16_t(*)[72])smem;            // [0, 9216)  overlay
  bf16_t (*vT)[72] = (bf16_t(*)[72])(smem + 9216);   // [9216, 13824) overlay
  int h = blockIdx.x % 24;
  int b = blockIdx.x / 24;
  int lane = threadIdx.x;
  float ls = __expf(fminf(logit_scale[h], 4.6051701859880914f));  // ln(100)
  size_t base = ((size_t)b * 24 + h) * 2048;
  const bf16_t* qrow = qkv + base + lane * 32;
  const bf16_t* krow = qkv + (size_t)50331648 + base + lane * 32;
  const bf16_t* vrow = qkv + (size_t)100663296 + base + lane * 32;
  bf16x8 vreg[4];
#pragma unroll
  for (int i = 0; i < 4; ++i) vreg[i] = *(const bf16x8*)(vrow + i * 8);
  {  // q: normalize + logit scale (f32), store bf16
    bf16x8 r[4];
#pragma unroll
    for (int i = 0; i < 4; ++i) r[i] = *(const bf16x8*)(qrow + i * 8);
    float f[32], sq = 0.f;
#pragma unroll
    for (int i = 0; i < 4; ++i)
#pragma unroll
      for (int j = 0; j < 8; ++j) { float x = (float)r[i][j]; f[i * 8 + j] = x; sq += x * x; }
    float sc = ls / fmaxf(sqrtf(sq), 1e-12f);
#pragma unroll
    for (int i = 0; i < 4; ++i) {
      bf16x8 w;
#pragma unroll
      for (int j = 0; j < 8; ++j) w[j] = (bf16_t)(f[i * 8 + j] * sc);
      *(bf16x8*)&qs[lane][i * 8] = w;
    }
  }
  {  // k: normalize
    bf16x8 r[4];
#pragma unroll
    for (int i = 0; i < 4; ++i) r[i] = *(const bf16x8*)(krow + i * 8);
    float f[32], sq = 0.f;
#pragma unroll
    for (int i = 0; i < 4; ++i)
#pragma unroll
      for (int j = 0; j < 8; ++j) { float x = (float)r[i][j]; f[i * 8 + j] = x; sq += x * x; }
    float sc = 1.f / fmaxf(sqrtf(sq), 1e-12f);
#pragma unroll
    for (int i = 0; i < 4; ++i) {
      bf16x8 w;
#pragma unroll
      for (int j = 0; j < 8; ++j) w[j] = (bf16_t)(f[i * 8 + j] * sc);
      *(bf16x8*)&kk[lane][i * 8] = w;
    }
  }
  __syncthreads();
  // S = q_n @ k_n^T
  f32x4 sacc[4][4] = {};
  {
    bf16x8 qa[4], kb[4];
#pragma unroll
    for (int mr = 0; mr < 4; ++mr)
      qa[mr] = *(bf16x8*)&qs[mr * 16 + (lane & 15)][(lane >> 4) * 8];
#pragma unroll
    for (int nc = 0; nc < 4; ++nc)
      kb[nc] = *(bf16x8*)&kk[nc * 16 + (lane & 15)][(lane >> 4) * 8];
    SP1;
#pragma unroll
    for (int mr = 0; mr < 4; ++mr)
#pragma unroll
      for (int nc = 0; nc < 4; ++nc)
        sacc[mr][nc] = mfma16(qa[mr], kb[nc], sacc[mr][nc]);
    SP0;
  }
  __syncthreads();
  {  // v transpose into vT (qs/kk now dead; single-wave in-order DS)
#pragma unroll
    for (int i = 0; i < 4; ++i)
#pragma unroll
      for (int j = 0; j < 8; ++j) vT[i * 8 + j][lane] = vreg[i][j];
  }
  // bias + exp (no max pass); raw exp to P, row-sums in regs
  const float* bh = bias + h * 4096;
  int hi4 = (lane >> 4) * 4;
  float rsum[4][4];
#pragma unroll
  for (int mr = 0; mr < 4; ++mr)
#pragma unroll
    for (int j = 0; j < 4; ++j) {
      int r = mr * 16 + hi4 + j;
      float v0 = __expf(sacc[mr][0][j] + bh[r * 64 + 0 + (lane & 15)]);
      float v1 = __expf(sacc[mr][1][j] + bh[r * 64 + 16 + (lane & 15)]);
      float v2 = __expf(sacc[mr][2][j] + bh[r * 64 + 32 + (lane & 15)]);
      float v3 = __expf(sacc[mr][3][j] + bh[r * 64 + 48 + (lane & 15)]);
      float sum = v0 + v1 + v2 + v3;
#pragma unroll
      for (int off = 1; off < 16; off <<= 1) sum += __shfl_xor(sum, off, 64);
      rsum[mr][j] = sum;
      ps[r][0 + (lane & 15)] = (bf16_t)v0;
      ps[r][16 + (lane & 15)] = (bf16_t)v1;
      ps[r][32 + (lane & 15)] = (bf16_t)v2;
      ps[r][48 + (lane & 15)] = (bf16_t)v3;
    }
  __syncthreads();
  // O = (P @ v) / rowsum
  f32x4 oacc[4][2] = {};
#pragma unroll
  for (int ks_ = 0; ks_ < 2; ++ks_) {
    bf16x8 pa[4], vb[2];
#pragma unroll
    for (int mr = 0; mr < 4; ++mr)
      pa[mr] = *(bf16x8*)&ps[mr * 16 + (lane & 15)][ks_ * 32 + (lane >> 4) * 8];
#pragma unroll
    for (int c2 = 0; c2 < 2; ++c2)
      vb[c2] = *(bf16x8*)&vT[c2 * 16 + (lane & 15)][ks_ * 32 + (lane >> 4) * 8];
    SP1;
#pragma unroll
    for (int mr = 0; mr < 4; ++mr)
#pragma unroll
      for (int c2 = 0; c2 < 2; ++c2)
        oacc[mr][c2] = mfma16(pa[mr], vb[c2], oacc[mr][c2]);
    SP0;
  }
#pragma unroll
  for (int mr = 0; mr < 4; ++mr) {
    float rinv[4];
#pragma unroll
    for (int j = 0; j < 4; ++j) rinv[j] = 1.f / rsum[mr][j];
#pragma unroll
    for (int c2 = 0; c2 < 2; ++c2) {
      int d = c2 * 16 + (lane & 15);
#pragma unroll
      for (int j = 0; j < 4; ++j) {
        int r = mr * 16 + hi4 + j;
        attn_out[((size_t)b * 64 + r) * 768 + h * 32 + d] =
            (bf16_t)(oacc[mr][c2][j] * rinv[j]);
      }
    }
  }
}

// ---------------- launch ----------------
extern "C" void kernel_launch(void* const* d_in, const int* in_sizes, int n_in,
                              void* d_out, int out_size, void* d_ws, size_t ws_size,
                              hipStream_t stream) {
  const float* x = (const float*)d_in[0];
  const float* qkv_w = (const float*)d_in[1];
  const float* qkv_b = (const float*)d_in[2];
  const float* proj_w = (const float*)d_in[3];
  const float* proj_b = (const float*)d_in[4];
  const float* cpb_w1 = (const float*)d_in[5];
  const float* cpb_b1 = (const float*)d_in[6];
  const float* cpb_w2 = (const float*)d_in[7];
  const float* logit_scale = (const float*)d_in[8];
  const float* rel_tab = (const float*)d_in[9];
  const int* rel_idx = (const int*)d_in[10];

  char* ws = (char*)d_ws;
  float* bias = (float*)(ws + 32768);
  bf16_t* wTq = (bf16_t*)(ws + 425984);
  bf16_t* wTp = (bf16_t*)(ws + 3964928);
  bf16_t* qkv = (bf16_t*)(ws + 5144576);
  bf16_t* xb = (bf16_t*)(ws + 307134464);
  bf16_t* attn = xb;  // disjoint live ranges

  prep_kernel<<<4376, 256, 0, stream>>>(x, xb, qkv_w, wTq, proj_w, wTp,
                                        rel_tab, cpb_w1, cpb_b1, cpb_w2,
                                        rel_idx, bias);
  gemm_kernel<0, 2304, 768><<<2304, 512, 0, stream>>>(xb, wTq, qkv_b, qkv);
  attn_kernel<<<24576, 64, 0, stream>>>(qkv, bias, logit_scale, attn);
  gemm_kernel<1, 768, 768><<<768, 512, 0, stream>>>(attn, wTp, proj_b, d_out);
}

// Round 16
// 563.357 us; speedup vs baseline: 1.0007x; 1.0007x over previous
//
#include <hip/hip_runtime.h>
#include <hip/hip_bf16.h>

typedef __bf16 bf16_t;
typedef __bf16 bf16x8 __attribute__((ext_vector_type(8)));
typedef float f32x4 __attribute__((ext_vector_type(4)));

static __device__ __forceinline__ f32x4 mfma16(bf16x8 a, bf16x8 b, f32x4 c) {
  return __builtin_amdgcn_mfma_f32_16x16x32_bf16(a, b, c, 0, 0, 0);
}

static __device__ __forceinline__ void gload16(const void* g, void* l) {
  __builtin_amdgcn_global_load_lds(
      (const __attribute__((address_space(1))) void*)g,
      (__attribute__((address_space(3))) void*)l, 16, 0, 0);
}

#define BAR() __builtin_amdgcn_s_barrier()
#define SCHED0() __builtin_amdgcn_sched_barrier(0)
#define MEMFENCE() asm volatile("" ::: "memory")
#define BARF() do { BAR(); MEMFENCE(); SCHED0(); } while (0)
#define WAITVM4() do { asm volatile("s_waitcnt vmcnt(4)" ::: "memory"); SCHED0(); } while (0)
#define WAITVM0() do { asm volatile("s_waitcnt vmcnt(0)" ::: "memory"); SCHED0(); } while (0)
#define WAITLGKM0() do { asm volatile("s_waitcnt lgkmcnt(0)" ::: "memory"); SCHED0(); } while (0)
#define SP1 __builtin_amdgcn_s_setprio(1)
#define SP0 __builtin_amdgcn_s_setprio(0)

// == merged prep: cvt(x->bf16) | W^T cvt | CPB-MLP + bias expand (per-head) ==
// blocks [0,2048): cvt; [2048,3776): wTq; [3776,4352): wTp; [4352,4376): bias.
// Bias block h: tid<225 recomputes CPB column h (wave-uniform loads, ~2us
// total), then expands via rel_idx to bias[h][64][64]. Replaces the separate
// bias_expand launch (R9 attribution: this fold is innocent; the regression
// there was the attn-side scattered gather).
__global__ __launch_bounds__(256) void prep_kernel(
    const float* __restrict__ x, bf16_t* __restrict__ xb,
    const float* __restrict__ qkv_w, bf16_t* __restrict__ wTq,
    const float* __restrict__ proj_w, bf16_t* __restrict__ wTp,
    const float* __restrict__ table, const float* __restrict__ w1,
    const float* __restrict__ b1, const float* __restrict__ w2,
    const int* __restrict__ rel_idx, float* __restrict__ bias) {
  __shared__ __align__(16) char sm[4352];
  int blk = blockIdx.x;
  int tid = threadIdx.x;
  if (blk < 2048) {  // ---- cvt: x f32 -> xb bf16, n8 = 6291456 ----
    const int n8 = 6291456, stride = 2048 * 256;
    for (int i = blk * 256 + tid; i < n8; i += stride) {
      float4 a = ((const float4*)x)[2 * i];
      float4 b = ((const float4*)x)[2 * i + 1];
      bf16x8 w = {(bf16_t)a.x, (bf16_t)a.y, (bf16_t)a.z, (bf16_t)a.w,
                  (bf16_t)b.x, (bf16_t)b.y, (bf16_t)b.z, (bf16_t)b.w};
      ((bf16x8*)xb)[i] = w;
    }
    return;
  }
  if (blk < 4352) {  // ---- transpose W[K][N] -> WT[N][K] bf16, 32x32 tiles ----
    const float* W;
    bf16_t* WT;
    int K = 768, N, r;
    if (blk < 3776) { W = qkv_w; WT = wTq; N = 2304; r = blk - 2048; }
    else            { W = proj_w; WT = wTp; N = 768;  r = blk - 3776; }
    int nbx = N / 32;
    int n0 = (r % nbx) * 32, k0 = (r / nbx) * 32;
    float (*tile)[33] = (float(*)[33])sm;
    int tx = tid & 31, ty = tid >> 5;
#pragma unroll
    for (int i = 0; i < 32; i += 8)
      tile[ty + i][tx] = W[(size_t)(k0 + ty + i) * N + n0 + tx];
    __syncthreads();
#pragma unroll
    for (int i = 0; i < 32; i += 8)
      WT[(size_t)(n0 + ty + i) * K + k0 + tx] = (bf16_t)tile[tx][ty + i];
    return;
  }
  {  // ---- bias: one block per head; recompute CPB column + expand ----
    float* sbuf = (float*)sm;  // 225 floats
    int h = blk - 4352;
    if (tid < 225) {
      float c0 = table[2 * tid], c1 = table[2 * tid + 1];
      float s = 0.f;
      for (int j = 0; j < 512; ++j) {  // w1/b1/w2 loads wave-uniform -> scalar
        float hh = c0 * w1[j] + c1 * w1[512 + j] + b1[j];
        s += fmaxf(hh, 0.f) * w2[j * 24 + h];
      }
      sbuf[tid] = s;
    }
    __syncthreads();
    for (int nm = tid; nm < 4096; nm += 256)
      bias[h * 4096 + nm] = sbuf[rel_idx[nm]];
  }
}

// ============ GEMM: 256x256, BK=64, 8-phase counted-vmcnt (round-4/6) =======
// Known-good schedule (R6/R8/R10/R13/R14: QKV ~250us, MfmaUtil 41%, 0
// conflicts, stable +-2us over 6 runs). Do not perturb: R5 (4-phase) and
// R7 (counted-lgkm prefetch) both regressed.
template <int EPI, int NCOLS, int K>
__global__ __launch_bounds__(512, 2) void gemm_kernel(
    const bf16_t* __restrict__ A, const bf16_t* __restrict__ BT,
    const float* __restrict__ bias, void* __restrict__ outp) {
  constexpr int NT = NCOLS / 256;
  constexpr int Kb = K * 2;
  constexpr int nk = K / 64;
  constexpr int nIt = nk / 2;
  __shared__ __align__(16) char lds[131072];
  int tid = threadIdx.x;
  int wave = tid >> 6, lane = tid & 63;
  int wm = wave >> 2, wn = wave & 3;
  int cpx = gridDim.x >> 3;
  int wg = (blockIdx.x & 7) * cpx + (blockIdx.x >> 3);
  int mt = wg / NT, nt = wg % NT;
  int m0 = mt * 256, n0 = nt * 256;

  int srow = tid >> 3;
  int sbc = ((tid & 7) << 4) ^ ((srow & 7) << 4);
  const char* Ag = (const char*)A + (size_t)(m0 + srow) * Kb + sbc;
  const char* Bg = (const char*)BT + (size_t)(n0 + srow) * Kb + sbc;
  char* Al = lds + tid * 16;
  char* Bl = lds + 65536 + tid * 16;

#define ST_A(B_, H_, KT_)                                                     \
  do {                                                                        \
    gload16(Ag + (size_t)((H_) * 128) * Kb + (KT_) * 128,                     \
            Al + (B_) * 32768 + (H_) * 16384);                                \
    gload16(Ag + (size_t)((H_) * 128 + 64) * Kb + (KT_) * 128,                \
            Al + (B_) * 32768 + (H_) * 16384 + 8192);                         \
  } while (0)
#define ST_B(B_, H_, KT_)                                                     \
  do {                                                                        \
    gload16(Bg + (size_t)((H_) * 128) * Kb + (KT_) * 128,                     \
            Bl + (B_) * 32768 + (H_) * 16384);                                \
    gload16(Bg + (size_t)((H_) * 128 + 64) * Kb + (KT_) * 128,                \
            Bl + (B_) * 32768 + (H_) * 16384 + 8192);                         \
  } while (0)

  int r15 = lane & 15, hi = lane >> 4;
  int swz = (lane & 7) << 4;
  int c0 = (hi << 4) ^ swz;         // kk=0 byte-col
  int c1 = (64 | (hi << 4)) ^ swz;  // kk=1 byte-col
  const char* aBase = lds + wm * 16384 + r15 * 128;
  const char* bBase = lds + 65536 + (wn >> 1) * 16384 + (wn & 1) * 8192 + r15 * 128;

#define RD_B8(B_)                                                             \
  do {                                                                        \
    _Pragma("unroll") for (int nc = 0; nc < 4; ++nc) {                        \
      bfr[nc][0] = *(const bf16x8*)(bBase + (B_) * 32768 + nc * 2048 + c0);   \
      bfr[nc][1] = *(const bf16x8*)(bBase + (B_) * 32768 + nc * 2048 + c1);   \
    }                                                                         \
  } while (0)
#define RD_A4(B_, MRLO, C_)                                                   \
  do {                                                                        \
    _Pragma("unroll") for (int m_ = 0; m_ < 4; ++m_)                          \
        af[m_] = *(const bf16x8*)(aBase + (B_) * 32768 + ((MRLO) + m_) * 2048 + (C_)); \
  } while (0)
#define MF16(MRLO, KKI)                                                       \
  do {                                                                        \
    _Pragma("unroll") for (int m_ = 0; m_ < 4; ++m_)                          \
        _Pragma("unroll") for (int nc = 0; nc < 4; ++nc)                      \
            acc[(MRLO) + m_][nc] =                                            \
        mfma16(af[m_], bfr[nc][KKI], acc[(MRLO) + m_][nc]);                   \
  } while (0)

  f32x4 acc[8][4] = {};
  ST_B(0, 0, 0); ST_B(0, 1, 0);
  ST_A(0, 0, 0); ST_A(0, 1, 0);
  ST_B(1, 0, 1); ST_B(1, 1, 1);
  WAITVM4();
  BARF();

  for (int it = 0; it < nIt - 1; ++it) {
    int T = 2 * it;
    bf16x8 af[4], bfr[4][2];
    // ph1
    RD_B8(0); RD_A4(0, 0, c0);
    ST_A(1, 0, T + 1); ST_A(1, 1, T + 1);
    BAR(); WAITLGKM0();
    SP1; MF16(0, 0); SP0;
    BARF();
    // ph2
    RD_A4(0, 4, c0);
    ST_B(0, 0, T + 2);
    BAR(); WAITLGKM0();
    SP1; MF16(4, 0); SP0;
    BARF();
    // ph3
    RD_A4(0, 0, c1);
    ST_B(0, 1, T + 2);
    BAR(); WAITLGKM0();
    SP1; MF16(0, 1); SP0;
    BARF();
    // ph4
    RD_A4(0, 4, c1);
    BAR(); WAITLGKM0();
    SP1; MF16(4, 1); SP0;
    WAITVM4();
    BARF();
    // ph5
    RD_B8(1); RD_A4(1, 0, c0);
    ST_A(0, 0, T + 2);
    BAR(); WAITLGKM0();
    SP1; MF16(0, 0); SP0;
    BARF();
    // ph6
    RD_A4(1, 4, c0);
    ST_A(0, 1, T + 2);
    BAR(); WAITLGKM0();
    SP1; MF16(4, 0); SP0;
    BARF();
    // ph7
    RD_A4(1, 0, c1);
    ST_B(1, 0, T + 3);
    BAR(); WAITLGKM0();
    SP1; MF16(0, 1); SP0;
    BARF();
    // ph8
    RD_A4(1, 4, c1);
    ST_B(1, 1, T + 3);
    BAR(); WAITLGKM0();
    SP1; MF16(4, 1); SP0;
    WAITVM4();
    BARF();
  }
  {  // peeled final iter: T = nk-2; only A(nk-1) still needs staging (ph1)
    bf16x8 af[4], bfr[4][2];
    RD_B8(0); RD_A4(0, 0, c0);
    ST_A(1, 0, nk - 1); ST_A(1, 1, nk - 1);
    BAR(); WAITLGKM0();
    SP1; MF16(0, 0); SP0;
    BARF();
    RD_A4(0, 4, c0);
    BAR(); WAITLGKM0();
    SP1; MF16(4, 0); SP0;
    BARF();
    RD_A4(0, 0, c1);
    BAR(); WAITLGKM0();
    SP1; MF16(0, 1); SP0;
    BARF();
    RD_A4(0, 4, c1);
    BAR(); WAITLGKM0();
    SP1; MF16(4, 1); SP0;
    WAITVM0();
    BARF();
    RD_B8(1); RD_A4(1, 0, c0);
    BAR(); WAITLGKM0();
    SP1; MF16(0, 0); SP0;
    BARF();
    RD_A4(1, 4, c0);
    BAR(); WAITLGKM0();
    SP1; MF16(4, 0); SP0;
    BARF();
    RD_A4(1, 0, c1);
    BAR(); WAITLGKM0();
    SP1; MF16(0, 1); SP0;
    BARF();
    RD_A4(1, 4, c1);
    BAR(); WAITLGKM0();
    SP1; MF16(4, 1); SP0;
  }

  // ---- epilogue ----
  int hi4 = hi * 4;
  if constexpr (EPI == 0) {
    bf16_t* out = (bf16_t*)outp;
    int sidx = n0 / 768;
#pragma unroll
    for (int mr = 0; mr < 8; ++mr)
#pragma unroll
      for (int nc = 0; nc < 4; ++nc) {
        int gcol = n0 + wn * 64 + nc * 16 + r15;
        int within = gcol - sidx * 768;
        int h = within >> 5, d = within & 31;
        float bv = bias[gcol];
#pragma unroll
        for (int j = 0; j < 4; ++j) {
          int grow = m0 + wm * 128 + mr * 16 + hi4 + j;
          int bwin = grow >> 6, nn = grow & 63;
          size_t off = ((((size_t)sidx * 1024 + bwin) * 24 + h) * 64 + nn) * 32 + d;
          out[off] = (bf16_t)(acc[mr][nc][j] + bv);
        }
      }
  } else {
    float* out = (float*)outp;
#pragma unroll
    for (int mr = 0; mr < 8; ++mr)
#pragma unroll
      for (int nc = 0; nc < 4; ++nc) {
        int gcol = n0 + wn * 64 + nc * 16 + r15;
        float bv = bias[gcol];
#pragma unroll
        for (int j = 0; j < 4; ++j) {
          int grow = m0 + wm * 128 + mr * 16 + hi4 + j;
          out[(size_t)grow * NCOLS + gcol] = acc[mr][nc][j] + bv;
        }
      }
  }
#undef ST_A
#undef ST_B
#undef RD_B8
#undef RD_A4
#undef MF16
}

// ---------------- Attention: one wave per (window, head) ----------------
// Byte-identical to R14 (best measured). LDS 13824 is alignment-minimal:
// ds_read_b128 rows must be 16B-aligned => strides multiple of 8 elems;
// 40/72 are the smallest conflict-free choices. b-major grid (neutral).
__global__ __launch_bounds__(64) void attn_kernel(
    const bf16_t* __restrict__ qkv, const float* __restrict__ bias,
    const float* __restrict__ logit_scale, bf16_t* __restrict__ attn_out) {
  __shared__ __align__(16) char smem[13824];
  bf16_t (*qs)[40] = (bf16_t(*)[40])smem;            // [0, 5120)
  bf16_t (*kk)[40] = (bf16_t(*)[40])(smem + 5120);   // [5120, 10240)
  bf16_t (*ps)[72] = (bf16_t(*)[72])smem;            // [0, 9216)  overlay
  bf16_t (*vT)[72] = (bf16_t(*)[72])(smem + 9216);   // [9216, 13824) overlay
  int h = blockIdx.x % 24;
  int b = blockIdx.x / 24;
  int lane = threadIdx.x;
  float ls = __expf(fminf(logit_scale[h], 4.6051701859880914f));  // ln(100)
  size_t base = ((size_t)b * 24 + h) * 2048;
  const bf16_t* qrow = qkv + base + lane * 32;
  const bf16_t* krow = qkv + (size_t)50331648 + base + lane * 32;
  const bf16_t* vrow = qkv + (size_t)100663296 + base + lane * 32;
  bf16x8 vreg[4];
#pragma unroll
  for (int i = 0; i < 4; ++i) vreg[i] = *(const bf16x8*)(vrow + i * 8);
  {  // q: normalize + logit scale (f32), store bf16
    bf16x8 r[4];
#pragma unroll
    for (int i = 0; i < 4; ++i) r[i] = *(const bf16x8*)(qrow + i * 8);
    float f[32], sq = 0.f;
#pragma unroll
    for (int i = 0; i < 4; ++i)
#pragma unroll
      for (int j = 0; j < 8; ++j) { float x = (float)r[i][j]; f[i * 8 + j] = x; sq += x * x; }
    float sc = ls / fmaxf(sqrtf(sq), 1e-12f);
#pragma unroll
    for (int i = 0; i < 4; ++i) {
      bf16x8 w;
#pragma unroll
      for (int j = 0; j < 8; ++j) w[j] = (bf16_t)(f[i * 8 + j] * sc);
      *(bf16x8*)&qs[lane][i * 8] = w;
    }
  }
  {  // k: normalize
    bf16x8 r[4];
#pragma unroll
    for (int i = 0; i < 4; ++i) r[i] = *(const bf16x8*)(krow + i * 8);
    float f[32], sq = 0.f;
#pragma unroll
    for (int i = 0; i < 4; ++i)
#pragma unroll
      for (int j = 0; j < 8; ++j) { float x = (float)r[i][j]; f[i * 8 + j] = x; sq += x * x; }
    float sc = 1.f / fmaxf(sqrtf(sq), 1e-12f);
#pragma unroll
    for (int i = 0; i < 4; ++i) {
      bf16x8 w;
#pragma unroll
      for (int j = 0; j < 8; ++j) w[j] = (bf16_t)(f[i * 8 + j] * sc);
      *(bf16x8*)&kk[lane][i * 8] = w;
    }
  }
  __syncthreads();
  // S = q_n @ k_n^T
  f32x4 sacc[4][4] = {};
  {
    bf16x8 qa[4], kb[4];
#pragma unroll
    for (int mr = 0; mr < 4; ++mr)
      qa[mr] = *(bf16x8*)&qs[mr * 16 + (lane & 15)][(lane >> 4) * 8];
#pragma unroll
    for (int nc = 0; nc < 4; ++nc)
      kb[nc] = *(bf16x8*)&kk[nc * 16 + (lane & 15)][(lane >> 4) * 8];
    SP1;
#pragma unroll
    for (int mr = 0; mr < 4; ++mr)
#pragma unroll
      for (int nc = 0; nc < 4; ++nc)
        sacc[mr][nc] = mfma16(qa[mr], kb[nc], sacc[mr][nc]);
    SP0;
  }
  __syncthreads();
  {  // v transpose into vT (qs/kk now dead; single-wave in-order DS)
#pragma unroll
    for (int i = 0; i < 4; ++i)
#pragma unroll
      for (int j = 0; j < 8; ++j) vT[i * 8 + j][lane] = vreg[i][j];
  }
  // bias + exp (no max pass); raw exp to P, row-sums in regs
  const float* bh = bias + h * 4096;
  int hi4 = (lane >> 4) * 4;
  float rsum[4][4];
#pragma unroll
  for (int mr = 0; mr < 4; ++mr)
#pragma unroll
    for (int j = 0; j < 4; ++j) {
      int r = mr * 16 + hi4 + j;
      float v0 = __expf(sacc[mr][0][j] + bh[r * 64 + 0 + (lane & 15)]);
      float v1 = __expf(sacc[mr][1][j] + bh[r * 64 + 16 + (lane & 15)]);
      float v2 = __expf(sacc[mr][2][j] + bh[r * 64 + 32 + (lane & 15)]);
      float v3 = __expf(sacc[mr][3][j] + bh[r * 64 + 48 + (lane & 15)]);
      float sum = v0 + v1 + v2 + v3;
#pragma unroll
      for (int off = 1; off < 16; off <<= 1) sum += __shfl_xor(sum, off, 64);
      rsum[mr][j] = sum;
      ps[r][0 + (lane & 15)] = (bf16_t)v0;
      ps[r][16 + (lane & 15)] = (bf16_t)v1;
      ps[r][32 + (lane & 15)] = (bf16_t)v2;
      ps[r][48 + (lane & 15)] = (bf16_t)v3;
    }
  __syncthreads();
  // O = (P @ v) / rowsum
  f32x4 oacc[4][2] = {};
#pragma unroll
  for (int ks_ = 0; ks_ < 2; ++ks_) {
    bf16x8 pa[4], vb[2];
#pragma unroll
    for (int mr = 0; mr < 4; ++mr)
      pa[mr] = *(bf16x8*)&ps[mr * 16 + (lane & 15)][ks_ * 32 + (lane >> 4) * 8];
#pragma unroll
    for (int c2 = 0; c2 < 2; ++c2)
      vb[c2] = *(bf16x8*)&vT[c2 * 16 + (lane & 15)][ks_ * 32 + (lane >> 4) * 8];
    SP1;
#pragma unroll
    for (int mr = 0; mr < 4; ++mr)
#pragma unroll
      for (int c2 = 0; c2 < 2; ++c2)
        oacc[mr][c2] = mfma16(pa[mr], vb[c2], oacc[mr][c2]);
    SP0;
  }
#pragma unroll
  for (int mr = 0; mr < 4; ++mr) {
    float rinv[4];
#pragma unroll
    for (int j = 0; j < 4; ++j) rinv[j] = 1.f / rsum[mr][j];
#pragma unroll
    for (int c2 = 0; c2 < 2; ++c2) {
      int d = c2 * 16 + (lane & 15);
#pragma unroll
      for (int j = 0; j < 4; ++j) {
        int r = mr * 16 + hi4 + j;
        attn_out[((size_t)b * 64 + r) * 768 + h * 32 + d] =
            (bf16_t)(oacc[mr][c2][j] * rinv[j]);
      }
    }
  }
}

// ---------------- launch ----------------
extern "C" void kernel_launch(void* const* d_in, const int* in_sizes, int n_in,
                              void* d_out, int out_size, void* d_ws, size_t ws_size,
                              hipStream_t stream) {
  const float* x = (const float*)d_in[0];
  const float* qkv_w = (const float*)d_in[1];
  const float* qkv_b = (const float*)d_in[2];
  const float* proj_w = (const float*)d_in[3];
  const float* proj_b = (const float*)d_in[4];
  const float* cpb_w1 = (const float*)d_in[5];
  const float* cpb_b1 = (const float*)d_in[6];
  const float* cpb_w2 = (const float*)d_in[7];
  const float* logit_scale = (const float*)d_in[8];
  const float* rel_tab = (const float*)d_in[9];
  const int* rel_idx = (const int*)d_in[10];

  char* ws = (char*)d_ws;
  float* bias = (float*)(ws + 32768);
  bf16_t* wTq = (bf16_t*)(ws + 425984);
  bf16_t* wTp = (bf16_t*)(ws + 3964928);
  bf16_t* qkv = (bf16_t*)(ws + 5144576);
  bf16_t* xb = (bf16_t*)(ws + 307134464);
  bf16_t* attn = xb;  // disjoint live ranges

  prep_kernel<<<4376, 256, 0, stream>>>(x, xb, qkv_w, wTq, proj_w, wTp,
                                        rel_tab, cpb_w1, cpb_b1, cpb_w2,
                                        rel_idx, bias);
  gemm_kernel<0, 2304, 768><<<2304, 512, 0, stream>>>(xb, wTq, qkv_b, qkv);
  attn_kernel<<<24576, 64, 0, stream>>>(qkv, bias, logit_scale, attn);
  gemm_kernel<1, 768, 768><<<768, 512, 0, stream>>>(attn, wTp, proj_b, d_out);
}

// Round 17
// 532.144 us; speedup vs baseline: 1.0594x; 1.0587x over previous
//
#include <hip/hip_runtime.h>
#include <hip/hip_bf16.h>

typedef __bf16 bf16_t;
typedef __bf16 bf16x8 __attribute__((ext_vector_type(8)));
typedef float f32x4 __attribute__((ext_vector_type(4)));

static __device__ __forceinline__ f32x4 mfma16(bf16x8 a, bf16x8 b, f32x4 c) {
  return __builtin_amdgcn_mfma_f32_16x16x32_bf16(a, b, c, 0, 0, 0);
}

static __device__ __forceinline__ void gload16(const void* g, void* l) {
  __builtin_amdgcn_global_load_lds(
      (const __attribute__((address_space(1))) void*)g,
      (__attribute__((address_space(3))) void*)l, 16, 0, 0);
}

#define BAR() __builtin_amdgcn_s_barrier()
#define SCHED0() __builtin_amdgcn_sched_barrier(0)
#define MEMFENCE() asm volatile("" ::: "memory")
#define BARF() do { BAR(); MEMFENCE(); SCHED0(); } while (0)
#define WAITVM4() do { asm volatile("s_waitcnt vmcnt(4)" ::: "memory"); SCHED0(); } while (0)
#define WAITVM0() do { asm volatile("s_waitcnt vmcnt(0)" ::: "memory"); SCHED0(); } while (0)
#define WAITLGKM0() do { asm volatile("s_waitcnt lgkmcnt(0)" ::: "memory"); SCHED0(); } while (0)
#define SP1 __builtin_amdgcn_s_setprio(1)
#define SP0 __builtin_amdgcn_s_setprio(0)

// ======= merged prep: cvt(x->bf16) | W^T cvt (qkv_w, proj_w) | CPB MLP =======
// blocks [0,2048): cvt; [2048,3776): wTq; [3776,4352): wTp; [4352,4577): cpb.
// R16 lesson: do NOT fold the 512-point CPB dot into a serial per-thread
// loop (+29us latency chain). Keep the parallel hbuf + shuffle-reduce form.
__global__ __launch_bounds__(256) void prep_kernel(
    const float* __restrict__ x, bf16_t* __restrict__ xb,
    const float* __restrict__ qkv_w, bf16_t* __restrict__ wTq,
    const float* __restrict__ proj_w, bf16_t* __restrict__ wTp,
    const float* __restrict__ table, const float* __restrict__ w1,
    const float* __restrict__ b1, const float* __restrict__ w2,
    float* __restrict__ bias_table) {
  __shared__ __align__(16) char sm[4352];
  int blk = blockIdx.x;
  int tid = threadIdx.x;
  if (blk < 2048) {  // ---- cvt: x f32 -> xb bf16, n8 = 6291456 ----
    const int n8 = 6291456, stride = 2048 * 256;
    for (int i = blk * 256 + tid; i < n8; i += stride) {
      float4 a = ((const float4*)x)[2 * i];
      float4 b = ((const float4*)x)[2 * i + 1];
      bf16x8 w = {(bf16_t)a.x, (bf16_t)a.y, (bf16_t)a.z, (bf16_t)a.w,
                  (bf16_t)b.x, (bf16_t)b.y, (bf16_t)b.z, (bf16_t)b.w};
      ((bf16x8*)xb)[i] = w;
    }
    return;
  }
  if (blk < 4352) {  // ---- transpose W[K][N] -> WT[N][K] bf16, 32x32 tiles ----
    const float* W;
    bf16_t* WT;
    int K = 768, N, r;
    if (blk < 3776) { W = qkv_w; WT = wTq; N = 2304; r = blk - 2048; }
    else            { W = proj_w; WT = wTp; N = 768;  r = blk - 3776; }
    int nbx = N / 32;
    int n0 = (r % nbx) * 32, k0 = (r / nbx) * 32;
    float (*tile)[33] = (float(*)[33])sm;
    int tx = tid & 31, ty = tid >> 5;
#pragma unroll
    for (int i = 0; i < 32; i += 8)
      tile[ty + i][tx] = W[(size_t)(k0 + ty + i) * N + n0 + tx];
    __syncthreads();
#pragma unroll
    for (int i = 0; i < 32; i += 8)
      WT[(size_t)(n0 + ty + i) * K + k0 + tx] = (bf16_t)tile[tx][ty + i];
    return;
  }
  {  // ---- CPB MLP: bias_table[t][24], t = blk-4352 (parallel reduce) ----
    float* hbuf = (float*)sm;
    int t = blk - 4352;
    float c0 = table[2 * t], c1 = table[2 * t + 1];
    for (int u = tid; u < 512; u += 256) {
      float h = c0 * w1[u] + c1 * w1[512 + u] + b1[u];
      hbuf[u] = h > 0.f ? h : 0.f;
    }
    __syncthreads();
    int wave = tid >> 6, lane = tid & 63;
    for (int hh = wave * 6; hh < wave * 6 + 6; ++hh) {
      float s = 0.f;
      for (int jj = lane; jj < 512; jj += 64) s += hbuf[jj] * w2[jj * 24 + hh];
#pragma unroll
      for (int off = 32; off > 0; off >>= 1) s += __shfl_down(s, off, 64);
      if (lane == 0) bias_table[t * 24 + hh] = s;
    }
  }
}

// ---------------- bias expand: table -> bias[24][64][64] ----------------
__global__ __launch_bounds__(256) void bias_expand_kernel(
    const float* __restrict__ bias_table, const int* __restrict__ idx,
    float* __restrict__ bias) {
  int h = blockIdx.x;
  for (int nm = threadIdx.x; nm < 4096; nm += 256)
    bias[h * 4096 + nm] = bias_table[idx[nm] * 24 + h];
}

// ============ GEMM: 256x256, BK=64, 8-phase counted-vmcnt (round-4/6) =======
// Known-good schedule (R6/R8/R10/R13/R14/R16: QKV ~250us, MfmaUtil 41%, 0
// conflicts, stable over 7 runs). Do not perturb: R5 (4-phase) and R7
// (counted-lgkm prefetch) both regressed.
template <int EPI, int NCOLS, int K>
__global__ __launch_bounds__(512, 2) void gemm_kernel(
    const bf16_t* __restrict__ A, const bf16_t* __restrict__ BT,
    const float* __restrict__ bias, void* __restrict__ outp) {
  constexpr int NT = NCOLS / 256;
  constexpr int Kb = K * 2;
  constexpr int nk = K / 64;
  constexpr int nIt = nk / 2;
  __shared__ __align__(16) char lds[131072];
  int tid = threadIdx.x;
  int wave = tid >> 6, lane = tid & 63;
  int wm = wave >> 2, wn = wave & 3;
  int cpx = gridDim.x >> 3;
  int wg = (blockIdx.x & 7) * cpx + (blockIdx.x >> 3);
  int mt = wg / NT, nt = wg % NT;
  int m0 = mt * 256, n0 = nt * 256;

  int srow = tid >> 3;
  int sbc = ((tid & 7) << 4) ^ ((srow & 7) << 4);
  const char* Ag = (const char*)A + (size_t)(m0 + srow) * Kb + sbc;
  const char* Bg = (const char*)BT + (size_t)(n0 + srow) * Kb + sbc;
  char* Al = lds + tid * 16;
  char* Bl = lds + 65536 + tid * 16;

#define ST_A(B_, H_, KT_)                                                     \
  do {                                                                        \
    gload16(Ag + (size_t)((H_) * 128) * Kb + (KT_) * 128,                     \
            Al + (B_) * 32768 + (H_) * 16384);                                \
    gload16(Ag + (size_t)((H_) * 128 + 64) * Kb + (KT_) * 128,                \
            Al + (B_) * 32768 + (H_) * 16384 + 8192);                         \
  } while (0)
#define ST_B(B_, H_, KT_)                                                     \
  do {                                                                        \
    gload16(Bg + (size_t)((H_) * 128) * Kb + (KT_) * 128,                     \
            Bl + (B_) * 32768 + (H_) * 16384);                                \
    gload16(Bg + (size_t)((H_) * 128 + 64) * Kb + (KT_) * 128,                \
            Bl + (B_) * 32768 + (H_) * 16384 + 8192);                         \
  } while (0)

  int r15 = lane & 15, hi = lane >> 4;
  int swz = (lane & 7) << 4;
  int c0 = (hi << 4) ^ swz;         // kk=0 byte-col
  int c1 = (64 | (hi << 4)) ^ swz;  // kk=1 byte-col
  const char* aBase = lds + wm * 16384 + r15 * 128;
  const char* bBase = lds + 65536 + (wn >> 1) * 16384 + (wn & 1) * 8192 + r15 * 128;

#define RD_B8(B_)                                                             \
  do {                                                                        \
    _Pragma("unroll") for (int nc = 0; nc < 4; ++nc) {                        \
      bfr[nc][0] = *(const bf16x8*)(bBase + (B_) * 32768 + nc * 2048 + c0);   \
      bfr[nc][1] = *(const bf16x8*)(bBase + (B_) * 32768 + nc * 2048 + c1);   \
    }                                                                         \
  } while (0)
#define RD_A4(B_, MRLO, C_)                                                   \
  do {                                                                        \
    _Pragma("unroll") for (int m_ = 0; m_ < 4; ++m_)                          \
        af[m_] = *(const bf16x8*)(aBase + (B_) * 32768 + ((MRLO) + m_) * 2048 + (C_)); \
  } while (0)
#define MF16(MRLO, KKI)                                                       \
  do {                                                                        \
    _Pragma("unroll") for (int m_ = 0; m_ < 4; ++m_)                          \
        _Pragma("unroll") for (int nc = 0; nc < 4; ++nc)                      \
            acc[(MRLO) + m_][nc] =                                            \
        mfma16(af[m_], bfr[nc][KKI], acc[(MRLO) + m_][nc]);                   \
  } while (0)

  f32x4 acc[8][4] = {};
  ST_B(0, 0, 0); ST_B(0, 1, 0);
  ST_A(0, 0, 0); ST_A(0, 1, 0);
  ST_B(1, 0, 1); ST_B(1, 1, 1);
  WAITVM4();
  BARF();

  for (int it = 0; it < nIt - 1; ++it) {
    int T = 2 * it;
    bf16x8 af[4], bfr[4][2];
    // ph1
    RD_B8(0); RD_A4(0, 0, c0);
    ST_A(1, 0, T + 1); ST_A(1, 1, T + 1);
    BAR(); WAITLGKM0();
    SP1; MF16(0, 0); SP0;
    BARF();
    // ph2
    RD_A4(0, 4, c0);
    ST_B(0, 0, T + 2);
    BAR(); WAITLGKM0();
    SP1; MF16(4, 0); SP0;
    BARF();
    // ph3
    RD_A4(0, 0, c1);
    ST_B(0, 1, T + 2);
    BAR(); WAITLGKM0();
    SP1; MF16(0, 1); SP0;
    BARF();
    // ph4
    RD_A4(0, 4, c1);
    BAR(); WAITLGKM0();
    SP1; MF16(4, 1); SP0;
    WAITVM4();
    BARF();
    // ph5
    RD_B8(1); RD_A4(1, 0, c0);
    ST_A(0, 0, T + 2);
    BAR(); WAITLGKM0();
    SP1; MF16(0, 0); SP0;
    BARF();
    // ph6
    RD_A4(1, 4, c0);
    ST_A(0, 1, T + 2);
    BAR(); WAITLGKM0();
    SP1; MF16(4, 0); SP0;
    BARF();
    // ph7
    RD_A4(1, 0, c1);
    ST_B(1, 0, T + 3);
    BAR(); WAITLGKM0();
    SP1; MF16(0, 1); SP0;
    BARF();
    // ph8
    RD_A4(1, 4, c1);
    ST_B(1, 1, T + 3);
    BAR(); WAITLGKM0();
    SP1; MF16(4, 1); SP0;
    WAITVM4();
    BARF();
  }
  {  // peeled final iter: T = nk-2; only A(nk-1) still needs staging (ph1)
    bf16x8 af[4], bfr[4][2];
    RD_B8(0); RD_A4(0, 0, c0);
    ST_A(1, 0, nk - 1); ST_A(1, 1, nk - 1);
    BAR(); WAITLGKM0();
    SP1; MF16(0, 0); SP0;
    BARF();
    RD_A4(0, 4, c0);
    BAR(); WAITLGKM0();
    SP1; MF16(4, 0); SP0;
    BARF();
    RD_A4(0, 0, c1);
    BAR(); WAITLGKM0();
    SP1; MF16(0, 1); SP0;
    BARF();
    RD_A4(0, 4, c1);
    BAR(); WAITLGKM0();
    SP1; MF16(4, 1); SP0;
    WAITVM0();
    BARF();
    RD_B8(1); RD_A4(1, 0, c0);
    BAR(); WAITLGKM0();
    SP1; MF16(0, 0); SP0;
    BARF();
    RD_A4(1, 4, c0);
    BAR(); WAITLGKM0();
    SP1; MF16(4, 0); SP0;
    BARF();
    RD_A4(1, 0, c1);
    BAR(); WAITLGKM0();
    SP1; MF16(0, 1); SP0;
    BARF();
    RD_A4(1, 4, c1);
    BAR(); WAITLGKM0();
    SP1; MF16(4, 1); SP0;
  }

  // ---- epilogue ----
  int hi4 = hi * 4;
  if constexpr (EPI == 0) {
    bf16_t* out = (bf16_t*)outp;
    int sidx = n0 / 768;
#pragma unroll
    for (int mr = 0; mr < 8; ++mr)
#pragma unroll
      for (int nc = 0; nc < 4; ++nc) {
        int gcol = n0 + wn * 64 + nc * 16 + r15;
        int within = gcol - sidx * 768;
        int h = within >> 5, d = within & 31;
        float bv = bias[gcol];
#pragma unroll
        for (int j = 0; j < 4; ++j) {
          int grow = m0 + wm * 128 + mr * 16 + hi4 + j;
          int bwin = grow >> 6, nn = grow & 63;
          size_t off = ((((size_t)sidx * 1024 + bwin) * 24 + h) * 64 + nn) * 32 + d;
          out[off] = (bf16_t)(acc[mr][nc][j] + bv);
        }
      }
  } else {
    float* out = (float*)outp;
#pragma unroll
    for (int mr = 0; mr < 8; ++mr)
#pragma unroll
      for (int nc = 0; nc < 4; ++nc) {
        int gcol = n0 + wn * 64 + nc * 16 + r15;
        float bv = bias[gcol];
#pragma unroll
        for (int j = 0; j < 4; ++j) {
          int grow = m0 + wm * 128 + mr * 16 + hi4 + j;
          out[(size_t)grow * NCOLS + gcol] = acc[mr][nc][j] + bv;
        }
      }
  }
#undef ST_A
#undef ST_B
#undef RD_B8
#undef RD_A4
#undef MF16
}

// ---------------- Attention: one wave per (window, head) ----------------
// R14 version (best measured): no-max softmax, deferred normalization,
// expanded-bias coalesced reads, early v-reg load, vT into dead kk tail,
// T5 setprio, b-major grid. LDS 13824 (alignment-minimal; 11 blocks/CU).
__global__ __launch_bounds__(64) void attn_kernel(
    const bf16_t* __restrict__ qkv, const float* __restrict__ bias,
    const float* __restrict__ logit_scale, bf16_t* __restrict__ attn_out) {
  __shared__ __align__(16) char smem[13824];
  bf16_t (*qs)[40] = (bf16_t(*)[40])smem;            // [0, 5120)
  bf16_t (*kk)[40] = (bf16_t(*)[40])(smem + 5120);   // [5120, 10240)
  bf16_t (*ps)[72] = (bf16_t(*)[72])smem;            // [0, 9216)  overlay
  bf16_t (*vT)[72] = (bf16_t(*)[72])(smem + 9216);   // [9216, 13824) overlay
  int h = blockIdx.x % 24;
  int b = blockIdx.x / 24;
  int lane = threadIdx.x;
  float ls = __expf(fminf(logit_scale[h], 4.6051701859880914f));  // ln(100)
  size_t base = ((size_t)b * 24 + h) * 2048;
  const bf16_t* qrow = qkv + base + lane * 32;
  const bf16_t* krow = qkv + (size_t)50331648 + base + lane * 32;
  const bf16_t* vrow = qkv + (size_t)100663296 + base + lane * 32;
  bf16x8 vreg[4];
#pragma unroll
  for (int i = 0; i < 4; ++i) vreg[i] = *(const bf16x8*)(vrow + i * 8);
  {  // q: normalize + logit scale (f32), store bf16
    bf16x8 r[4];
#pragma unroll
    for (int i = 0; i < 4; ++i) r[i] = *(const bf16x8*)(qrow + i * 8);
    float f[32], sq = 0.f;
#pragma unroll
    for (int i = 0; i < 4; ++i)
#pragma unroll
      for (int j = 0; j < 8; ++j) { float x = (float)r[i][j]; f[i * 8 + j] = x; sq += x * x; }
    float sc = ls / fmaxf(sqrtf(sq), 1e-12f);
#pragma unroll
    for (int i = 0; i < 4; ++i) {
      bf16x8 w;
#pragma unroll
      for (int j = 0; j < 8; ++j) w[j] = (bf16_t)(f[i * 8 + j] * sc);
      *(bf16x8*)&qs[lane][i * 8] = w;
    }
  }
  {  // k: normalize
    bf16x8 r[4];
#pragma unroll
    for (int i = 0; i < 4; ++i) r[i] = *(const bf16x8*)(krow + i * 8);
    float f[32], sq = 0.f;
#pragma unroll
    for (int i = 0; i < 4; ++i)
#pragma unroll
      for (int j = 0; j < 8; ++j) { float x = (float)r[i][j]; f[i * 8 + j] = x; sq += x * x; }
    float sc = 1.f / fmaxf(sqrtf(sq), 1e-12f);
#pragma unroll
    for (int i = 0; i < 4; ++i) {
      bf16x8 w;
#pragma unroll
      for (int j = 0; j < 8; ++j) w[j] = (bf16_t)(f[i * 8 + j] * sc);
      *(bf16x8*)&kk[lane][i * 8] = w;
    }
  }
  __syncthreads();
  // S = q_n @ k_n^T
  f32x4 sacc[4][4] = {};
  {
    bf16x8 qa[4], kb[4];
#pragma unroll
    for (int mr = 0; mr < 4; ++mr)
      qa[mr] = *(bf16x8*)&qs[mr * 16 + (lane & 15)][(lane >> 4) * 8];
#pragma unroll
    for (int nc = 0; nc < 4; ++nc)
      kb[nc] = *(bf16x8*)&kk[nc * 16 + (lane & 15)][(lane >> 4) * 8];
    SP1;
#pragma unroll
    for (int mr = 0; mr < 4; ++mr)
#pragma unroll
      for (int nc = 0; nc < 4; ++nc)
        sacc[mr][nc] = mfma16(qa[mr], kb[nc], sacc[mr][nc]);
    SP0;
  }
  __syncthreads();
  {  // v transpose into vT (qs/kk now dead; single-wave in-order DS)
#pragma unroll
    for (int i = 0; i < 4; ++i)
#pragma unroll
      for (int j = 0; j < 8; ++j) vT[i * 8 + j][lane] = vreg[i][j];
  }
  // bias + exp (no max pass); raw exp to P, row-sums in regs
  const float* bh = bias + h * 4096;
  int hi4 = (lane >> 4) * 4;
  float rsum[4][4];
#pragma unroll
  for (int mr = 0; mr < 4; ++mr)
#pragma unroll
    for (int j = 0; j < 4; ++j) {
      int r = mr * 16 + hi4 + j;
      float v0 = __expf(sacc[mr][0][j] + bh[r * 64 + 0 + (lane & 15)]);
      float v1 = __expf(sacc[mr][1][j] + bh[r * 64 + 16 + (lane & 15)]);
      float v2 = __expf(sacc[mr][2][j] + bh[r * 64 + 32 + (lane & 15)]);
      float v3 = __expf(sacc[mr][3][j] + bh[r * 64 + 48 + (lane & 15)]);
      float sum = v0 + v1 + v2 + v3;
#pragma unroll
      for (int off = 1; off < 16; off <<= 1) sum += __shfl_xor(sum, off, 64);
      rsum[mr][j] = sum;
      ps[r][0 + (lane & 15)] = (bf16_t)v0;
      ps[r][16 + (lane & 15)] = (bf16_t)v1;
      ps[r][32 + (lane & 15)] = (bf16_t)v2;
      ps[r][48 + (lane & 15)] = (bf16_t)v3;
    }
  __syncthreads();
  // O = (P @ v) / rowsum
  f32x4 oacc[4][2] = {};
#pragma unroll
  for (int ks_ = 0; ks_ < 2; ++ks_) {
    bf16x8 pa[4], vb[2];
#pragma unroll
    for (int mr = 0; mr < 4; ++mr)
      pa[mr] = *(bf16x8*)&ps[mr * 16 + (lane & 15)][ks_ * 32 + (lane >> 4) * 8];
#pragma unroll
    for (int c2 = 0; c2 < 2; ++c2)
      vb[c2] = *(bf16x8*)&vT[c2 * 16 + (lane & 15)][ks_ * 32 + (lane >> 4) * 8];
    SP1;
#pragma unroll
    for (int mr = 0; mr < 4; ++mr)
#pragma unroll
      for (int c2 = 0; c2 < 2; ++c2)
        oacc[mr][c2] = mfma16(pa[mr], vb[c2], oacc[mr][c2]);
    SP0;
  }
#pragma unroll
  for (int mr = 0; mr < 4; ++mr) {
    float rinv[4];
#pragma unroll
    for (int j = 0; j < 4; ++j) rinv[j] = 1.f / rsum[mr][j];
#pragma unroll
    for (int c2 = 0; c2 < 2; ++c2) {
      int d = c2 * 16 + (lane & 15);
#pragma unroll
      for (int j = 0; j < 4; ++j) {
        int r = mr * 16 + hi4 + j;
        attn_out[((size_t)b * 64 + r) * 768 + h * 32 + d] =
            (bf16_t)(oacc[mr][c2][j] * rinv[j]);
      }
    }
  }
}

// ---------------- launch ----------------
extern "C" void kernel_launch(void* const* d_in, const int* in_sizes, int n_in,
                              void* d_out, int out_size, void* d_ws, size_t ws_size,
                              hipStream_t stream) {
  const float* x = (const float*)d_in[0];
  const float* qkv_w = (const float*)d_in[1];
  const float* qkv_b = (const float*)d_in[2];
  const float* proj_w = (const float*)d_in[3];
  const float* proj_b = (const float*)d_in[4];
  const float* cpb_w1 = (const float*)d_in[5];
  const float* cpb_b1 = (const float*)d_in[6];
  const float* cpb_w2 = (const float*)d_in[7];
  const float* logit_scale = (const float*)d_in[8];
  const float* rel_tab = (const float*)d_in[9];
  const int* rel_idx = (const int*)d_in[10];

  char* ws = (char*)d_ws;
  float* bias_table = (float*)ws;
  float* bias = (float*)(ws + 32768);
  bf16_t* wTq = (bf16_t*)(ws + 425984);
  bf16_t* wTp = (bf16_t*)(ws + 3964928);
  bf16_t* qkv = (bf16_t*)(ws + 5144576);
  bf16_t* xb = (bf16_t*)(ws + 307134464);
  bf16_t* attn = xb;  // disjoint live ranges

  prep_kernel<<<4577, 256, 0, stream>>>(x, xb, qkv_w, wTq, proj_w, wTp,
                                        rel_tab, cpb_w1, cpb_b1, cpb_w2,
                                        bias_table);
  bias_expand_kernel<<<24, 256, 0, stream>>>(bias_table, rel_idx, bias);
  gemm_kernel<0, 2304, 768><<<2304, 512, 0, stream>>>(xb, wTq, qkv_b, qkv);
  attn_kernel<<<24576, 64, 0, stream>>>(qkv, bias, logit_scale, attn);
  gemm_kernel<1, 768, 768><<<768, 512, 0, stream>>>(attn, wTp, proj_b, d_out);
}